// Round 4
// baseline (265.394 us; speedup 1.0000x reference)
//
#include <hip/hip_runtime.h>
#include <stdint.h>

#define TT 512
#define BB 32
#define EE 512
#define HH 2048

typedef __attribute__((ext_vector_type(8))) short short8;   // 8 x bf16 (4 VGPRs)
typedef __attribute__((ext_vector_type(4))) float f32x4;    // MFMA accumulator

// LDS geometry (in shorts)
#define XROW 528            // 512 data + 16 pad: measured 0 bank conflicts (R1/R3);
                            // 520 gave 8.4M conflicts (R4). Row stride 1056 B = 16*66.
#define XBUF (16 * XROW)    // one 16-t chunk buffer = 8448 shorts (16.5 KB)

// Counted-vmcnt barriers (T3/T4). Each wave issues exactly 4 global_load_lds
// per stage; vmcnt(4) retires the OLDEST 4 (stage ch+1) while leaving the 4
// just-issued (stage ch+2) in flight across the barrier. lgkmcnt(0) orders
// all DS ops (a-frag reads, exch traffic) before the barrier.
#define BAR_VM4() asm volatile("s_waitcnt vmcnt(4) lgkmcnt(0)\n\ts_barrier" ::: "memory")
#define BAR_VM0() asm volatile("s_waitcnt vmcnt(0) lgkmcnt(0)\n\ts_barrier" ::: "memory")

static __device__ __forceinline__ float fast_exp(float x) {
    return __builtin_amdgcn_exp2f(x * 1.44269504f);
}
static __device__ __forceinline__ float fast_rcp(float x) {
    return __builtin_amdgcn_rcpf(x);
}

// Packed fp32->bf16 RNE convert: 1 instr per 2 elements (vs 4 int-ALU ops
// per element for the bit-twiddle). gfx950-verified instruction (T12).
static __device__ __forceinline__ unsigned cvtpk_bf16(float lo, float hi) {
    unsigned r;
    asm("v_cvt_pk_bf16_f32 %0, %1, %2" : "=v"(r) : "v"(lo), "v"(hi));
    return r;
}

// Async global->LDS DMA, 16 B/lane (wave-uniform LDS base + lane*16).
// Verified correct in R4 (passed, absmax 0.0039).
static __device__ __forceinline__ void load_lds16(const unsigned short* g, unsigned short* l) {
    __builtin_amdgcn_global_load_lds(
        (const __attribute__((address_space(1))) unsigned int*)(uintptr_t)g,
        (__attribute__((address_space(3))) unsigned int*)(uintptr_t)l,
        16, 0, 0);
}

// ---------------------------------------------------------------------------
// Pre-kernel: convert sent (T,B,E) fp32 and W (3H,E) fp32 to bf16 in ws.
// R8: v_cvt_pk_bf16_f32 (VALU cost /8) — this kernel was ~50 µs vs an 11 µs
// BW bound, i.e. VALU-bound on the scalar round-to-nearest-even emulation.
// ---------------------------------------------------------------------------
__global__ void convert_inputs(const float* __restrict__ X,
                               const float* __restrict__ W,
                               unsigned short* __restrict__ Xb,
                               unsigned short* __restrict__ Wb) {
    const int nX = TT * BB * EE;              // 8,388,608 (divisible by 8)
    int i = (blockIdx.x * blockDim.x + threadIdx.x) * 8;
    const float* src;
    unsigned short* dst;
    int j;
    if (i < nX) { src = X; dst = Xb; j = i; }
    else        { src = W; dst = Wb; j = i - nX; }
    float4 v0 = *(const float4*)(src + j);
    float4 v1 = *(const float4*)(src + j + 4);
    union { short8 s; unsigned u[4]; } o;
    o.u[0] = cvtpk_bf16(v0.x, v0.y);
    o.u[1] = cvtpk_bf16(v0.z, v0.w);
    o.u[2] = cvtpk_bf16(v1.x, v1.y);
    o.u[3] = cvtpk_bf16(v1.z, v1.w);
    *(short8*)(dst + j) = o.s;
}

// ---------------------------------------------------------------------------
// Fused QRNN kernel — R8: straight-line region (redundant tails) + split
// accumulator chains.
//
// R3 post-mortem: counted-vmcnt depth-2 was NEUTRAL -> the DMA drain was
// never the exposed latency. The region critical path is the s=0 wave's
// serial in-order issue: [a-frag reads | 3x8-deep dependent MFMA chains
// (wave stalls between dependent MFMAs) | ~400cyc tail behind `if(s==0)`].
// The tail has no data dependence on the MFMAs (rotation), but the branch
// stops the compiler from interleaving it into the MFMA stall gaps.
//
// Changes:
//  (a) BOTH k-half waves publish partials, BOTH read the partner's, BOTH
//      run the tail (bitwise-identical results; f32 a+b == b+a). The loop
//      body has NO branches -> compiler interleaves tail VALU/trans/DS ops
//      with MFMA stalls; VALU load spreads over all 4 SIMDs (was 2).
//  (b) Accumulators split even/odd k: 6 chains of depth 4 (was 3 of 8) ->
//      half the dependent-MFMA stall. +12 VGPR (~120 total + 96 AGPR W-pin
//      = ~216 < 256: 2 waves/SIMD preserved).
//  (c) Chunk 0 peeled so the steady-state body is fully unconditional.
//
// Hazard set (unchanged from R3 except exch is now [p][hi][s]):
//  (1) publish(ch) by wave s vs partner read in region ch+1: lgkmcnt(0) +
//      barrier(ch).
//  (2) partner-read(ch-1) in region ch vs re-publish of that slot in region
//      ch+2 (p has period 2): barrier(ch+1) with lgkmcnt(0) retires reads.
//  (3) X buf WAR: stage(ch+2) writes buf (ch+2)%3; last readers retired at
//      barrier(ch-1) (lgkmcnt(0)) before any wave stages in region ch.
//  (4) X buf RAW: region ch+1 reads buf (ch+1)%3; its 4 DMA loads are the
//      oldest outstanding at barrier(ch) -> vmcnt(4) retires them. Regions
//      30/31 use vmcnt(0) (no stage issued in 30 -> stage(31) not oldest-4).
//  (5) Barriers wave-uniform: ch uniform, no divergent barrier.
//  (6) carry/vmax: per-wave locals; both waves compute identical values from
//      identical summed partials (commutative add) -> no cross-wave handoff.
// ---------------------------------------------------------------------------
__launch_bounds__(256, 2)
__global__ void qrnn_fused(const unsigned short* __restrict__ Xb, // bf16 (T,B,E)
                           const unsigned short* __restrict__ Wb, // bf16 (3H,E)
                           const float* __restrict__ bias,        // (3H)
                           float* __restrict__ out)               // (B,H) fp32
{
    __shared__ unsigned short xlds[3 * XBUF];      // 50,688 B
    __shared__ float exch[2][2][2][64][12];        // 24,576 B  (total 75,264 B)

    const int tid  = threadIdx.x;
    const int wv   = tid >> 6;         // wave 0..3
    const int lane = tid & 63;
    const int q    = lane >> 4;        // quad 0..3
    const int c    = lane & 15;        // column within 16x16 tile
    const int hi   = wv >> 1;          // h-tile 0..1
    const int s    = wv & 1;           // k-half 0..1

    // XCD-aware swizzle: 2048 blocks = 8 XCDs x 4 batches x 64 h-groups.
    const int id   = blockIdx.x;       // 0..2047
    const int xcd  = id & 7;
    const int slot = id >> 3;          // 0..255 within this XCD
    const int b    = xcd * 4 + (slot >> 6);   // 4 batches per XCD
    const int hgrp = slot & 63;               // 64 h-groups per batch
    const int h    = hgrp * 32 + hi * 16 + c;

    // ---- preload W fragments (this wave's K half); pin into AGPRs ----
    // B-frag layout for 16x16x32: lane holds n = lane&15 (= h), k = q*8 + j.
    short8 wz[8], wf[8], wo[8];
    {
        const unsigned short* wzr = Wb + (size_t)h * EE            + s * 256;
        const unsigned short* wfr = Wb + (size_t)(HH + h) * EE     + s * 256;
        const unsigned short* wor = Wb + (size_t)(2 * HH + h) * EE + s * 256;
#pragma unroll
        for (int k = 0; k < 8; ++k) {
            int e0 = k * 32 + q * 8;
            wz[k] = *(const short8*)(wzr + e0);
            wf[k] = *(const short8*)(wfr + e0);
            wo[k] = *(const short8*)(wor + e0);
        }
    }
#pragma unroll
    for (int k = 0; k < 8; ++k) {
        asm volatile("" : "+a"(wz[k]), "+a"(wf[k]), "+a"(wo[k]));
    }

    // Bias enters once: only the s=0 partial carries it; the summed pair
    // (own + partner) then has it exactly once for BOTH waves.
    const float b0 = (s == 0) ? bias[h]          : 0.0f;
    const float b1 = (s == 0) ? bias[HH + h]     : 0.0f;
    const float b2 = (s == 0) ? bias[2 * HH + h] : 0.0f;

    float carry = 0.0f;
    float vmax  = -1e30f;

    // ---- staging: wave wv owns rows wv*4 .. wv*4+3 of each 16-t chunk ----
    const unsigned short* g0 = Xb + ((size_t)(wv * 4) * BB + b) * EE + lane * 8;
    unsigned short* l0 = &xlds[(wv * 4) * XROW];

    auto stage = [&](int n, int slt) {
        const unsigned short* g = g0 + (size_t)n * (16 * BB * EE);
        unsigned short* l = l0 + slt * XBUF;
#pragma unroll
        for (int i = 0; i < 4; ++i)
            load_lds16(g + (size_t)i * (BB * EE), l + i * XROW);
    };

    // tail for one chunk's fully-summed accumulators (ALL waves run this;
    // results are bitwise-identical across the s pair):
    // activations, 16-step affine scan (4 in-lane + cross-quad), carry, max.
    auto do_tail = [&](f32x4 az, f32x4 af, f32x4 ao) {
        float aa[4], mm[4], oo[4];
#pragma unroll
        for (int r = 0; r < 4; ++r) {
            float e2 = fast_exp(2.0f * az[r]);
            float z  = 1.0f - 2.0f * fast_rcp(e2 + 1.0f);  // tanh
            float f  = fast_rcp(1.0f + fast_exp(-af[r]));  // sigmoid
            float o  = fast_rcp(1.0f + fast_exp(-ao[r]));  // sigmoid
            aa[r] = f * z;
            mm[r] = 1.0f - f;
            oo[r] = o;
        }

        // affine scan: compose 4 steps, scan across quads
        float A = aa[0], M = mm[0];
#pragma unroll
        for (int r = 1; r < 4; ++r) { A = aa[r] + mm[r] * A; M = mm[r] * M; }

        float Ap = __shfl_up(A, 16, 64), Mp = __shfl_up(M, 16, 64);
        if (q >= 1) { A = A + M * Ap; M = M * Mp; }
        Ap = __shfl_up(A, 32, 64); Mp = __shfl_up(M, 32, 64);
        if (q >= 2) { A = A + M * Ap; M = M * Mp; }
        float Ae = __shfl_up(A, 16, 64), Me = __shfl_up(M, 16, 64);
        if (q == 0) { Ae = 0.0f; Me = 1.0f; }
        float cc = Ae + Me * carry;

#pragma unroll
        for (int r = 0; r < 4; ++r) {
            cc = aa[r] + mm[r] * cc;
            vmax = fmaxf(vmax, oo[r] * cc);
        }

        float cend = A + M * carry;
        carry = __shfl(cend, 48 + c, 64);
    };

    // ---- prologue: fill the depth-2 DMA pipeline ----
    stage(0, 0);
    stage(1, 1);
    BAR_VM4();   // retire stage(0); stage(1) stays in flight

    f32x4 prevz, prevf, prevo;   // own partials of chunk ch-1 (rotation state)

    // ---- peeled region 0: MFMA(0) + publish, no tail ----
    {
        stage(2, 2);
        const unsigned short* Abase = &xlds[0 * XBUF + c * XROW + s * 256 + q * 8];
        short8 a[8];
#pragma unroll
        for (int k = 0; k < 8; ++k)
            a[k] = *(const short8*)(Abase + k * 32);

        f32x4 az0 = {b0, b0, b0, b0}, az1 = {0.f, 0.f, 0.f, 0.f};
        f32x4 af0 = {b1, b1, b1, b1}, af1 = {0.f, 0.f, 0.f, 0.f};
        f32x4 ao0 = {b2, b2, b2, b2}, ao1 = {0.f, 0.f, 0.f, 0.f};
#pragma unroll
        for (int k = 0; k < 8; k += 2) {
            az0 = __builtin_amdgcn_mfma_f32_16x16x32_bf16(a[k],     wz[k],     az0, 0, 0, 0);
            az1 = __builtin_amdgcn_mfma_f32_16x16x32_bf16(a[k + 1], wz[k + 1], az1, 0, 0, 0);
            af0 = __builtin_amdgcn_mfma_f32_16x16x32_bf16(a[k],     wf[k],     af0, 0, 0, 0);
            af1 = __builtin_amdgcn_mfma_f32_16x16x32_bf16(a[k + 1], wf[k + 1], af1, 0, 0, 0);
            ao0 = __builtin_amdgcn_mfma_f32_16x16x32_bf16(a[k],     wo[k],     ao0, 0, 0, 0);
            ao1 = __builtin_amdgcn_mfma_f32_16x16x32_bf16(a[k + 1], wo[k + 1], ao1, 0, 0, 0);
        }
        prevz = az0 + az1; prevf = af0 + af1; prevo = ao0 + ao1;

        float* w = &exch[0][hi][s][lane][0];
        *(f32x4*)(w)     = prevz;
        *(f32x4*)(w + 4) = prevf;
        *(f32x4*)(w + 8) = prevo;

        BAR_VM4();   // retire stage(1); stage(2) in flight
    }

    // ---- steady state: fully branch-free region ----
    for (int ch = 1; ch < 32; ++ch) {
        const int buf = ch % 3;
        if (ch < 30) stage(ch + 2, (ch + 2) % 3);

        // a-frags for chunk ch (8 back-to-back b128)
        const unsigned short* Abase = &xlds[buf * XBUF + c * XROW + s * 256 + q * 8];
        short8 a[8];
#pragma unroll
        for (int k = 0; k < 8; ++k)
            a[k] = *(const short8*)(Abase + k * 32);

        // partner partials for tail(ch-1)
        const float* e = &exch[(ch - 1) & 1][hi][s ^ 1][lane][0];
        f32x4 pz = *(const f32x4*)(e);
        f32x4 pf = *(const f32x4*)(e + 4);
        f32x4 po = *(const f32x4*)(e + 8);

        // 24 MFMAs in 6 independent chains of depth 4
        f32x4 az0 = {b0, b0, b0, b0}, az1 = {0.f, 0.f, 0.f, 0.f};
        f32x4 af0 = {b1, b1, b1, b1}, af1 = {0.f, 0.f, 0.f, 0.f};
        f32x4 ao0 = {b2, b2, b2, b2}, ao1 = {0.f, 0.f, 0.f, 0.f};
#pragma unroll
        for (int k = 0; k < 8; k += 2) {
            az0 = __builtin_amdgcn_mfma_f32_16x16x32_bf16(a[k],     wz[k],     az0, 0, 0, 0);
            az1 = __builtin_amdgcn_mfma_f32_16x16x32_bf16(a[k + 1], wz[k + 1], az1, 0, 0, 0);
            af0 = __builtin_amdgcn_mfma_f32_16x16x32_bf16(a[k],     wf[k],     af0, 0, 0, 0);
            af1 = __builtin_amdgcn_mfma_f32_16x16x32_bf16(a[k + 1], wf[k + 1], af1, 0, 0, 0);
            ao0 = __builtin_amdgcn_mfma_f32_16x16x32_bf16(a[k],     wo[k],     ao0, 0, 0, 0);
            ao1 = __builtin_amdgcn_mfma_f32_16x16x32_bf16(a[k + 1], wo[k + 1], ao1, 0, 0, 0);
        }
        f32x4 az = az0 + az1, af = af0 + af1, ao = ao0 + ao1;

        // publish own partials for partner's tail(ch) next region
        float* w = &exch[ch & 1][hi][s][lane][0];
        *(f32x4*)(w)     = az;
        *(f32x4*)(w + 4) = af;
        *(f32x4*)(w + 8) = ao;

        // tail(ch-1): independent of the MFMAs above -> compiler interleaves
        // its VALU/trans/shuffles into the MFMA dependency stalls.
        do_tail(prevz + pz, prevf + pf, prevo + po);

        prevz = az; prevf = af; prevo = ao;

        if (ch < 30) BAR_VM4(); else BAR_VM0();
    }

    // ---- epilogue: tail(31) (published in region 31) ----
    {
        const float* e = &exch[1][hi][s ^ 1][lane][0];
        f32x4 pz = *(const f32x4*)(e);
        f32x4 pf = *(const f32x4*)(e + 4);
        f32x4 po = *(const f32x4*)(e + 8);
        do_tail(prevz + pz, prevf + pf, prevo + po);
    }

    vmax = fmaxf(vmax, __shfl_xor(vmax, 16, 64));
    vmax = fmaxf(vmax, __shfl_xor(vmax, 32, 64));
    if (s == 0 && q == 0) out[(size_t)b * HH + h] = vmax;
}

// ---------------------------------------------------------------------------
extern "C" void kernel_launch(void* const* d_in, const int* in_sizes, int n_in,
                              void* d_out, int out_size, void* d_ws, size_t ws_size,
                              hipStream_t stream) {
    const float* sent = (const float*)d_in[0];
    // d_in[1] = lengths (unused by the math)
    const float* W    = (const float*)d_in[2];
    const float* bias = (const float*)d_in[3];
    float* out        = (float*)d_out;

    const int nX = TT * BB * EE;        // 8,388,608
    const int nW = 3 * HH * EE;         // 3,145,728
    unsigned short* Xb = (unsigned short*)d_ws;
    unsigned short* Wb = Xb + nX;       // 16 MiB offset, 16B-aligned

    int totalVec = (nX + nW) / 8;       // 1,441,792 threads, exact cover
    convert_inputs<<<totalVec / 256, 256, 0, stream>>>(sent, W, Xb, Wb);

    dim3 grid(2048);                    // 1-D: swizzled to (xcd, b, hgrp) in-kernel
    qrnn_fused<<<grid, 256, 0, stream>>>(Xb, Wb, bias, out);
}

// Round 5
// 259.729 us; speedup vs baseline: 1.0218x; 1.0218x over previous
//
#include <hip/hip_runtime.h>
#include <stdint.h>

#define TT 512
#define BB 32
#define EE 512
#define HH 2048

typedef __attribute__((ext_vector_type(8))) short short8;   // 8 x bf16 (4 VGPRs)
typedef __attribute__((ext_vector_type(4))) float f32x4;    // MFMA accumulator

// LDS geometry (in shorts)
#define XROW 528            // 512 data + 16 pad: measured 0 bank conflicts (R1/R3/R4);
                            // 520 gave 8.4M conflicts. Row stride 1056 B = 16*66.
#define XBUF (16 * XROW)    // one 16-t chunk buffer = 8448 shorts (16.5 KB)

// Barrier: drain DMA (vmcnt) + all DS ops (lgkm), then s_barrier.
// R3 measured counted-vmcnt vs vmcnt(0) NEUTRAL -> keep the simple form.
#define BAR_VM0() asm volatile("s_waitcnt vmcnt(0) lgkmcnt(0)\n\ts_barrier" ::: "memory")

static __device__ __forceinline__ float fast_exp(float x) {
    return __builtin_amdgcn_exp2f(x * 1.44269504f);
}
static __device__ __forceinline__ float fast_rcp(float x) {
    return __builtin_amdgcn_rcpf(x);
}

// Packed fp32->bf16 RNE convert: 1 instr per 2 elements.
static __device__ __forceinline__ unsigned cvtpk_bf16(float lo, float hi) {
    unsigned r;
    asm("v_cvt_pk_bf16_f32 %0, %1, %2" : "=v"(r) : "v"(lo), "v"(hi));
    return r;
}

// Async global->LDS DMA, 16 B/lane (wave-uniform LDS base + lane*16).
static __device__ __forceinline__ void load_lds16(const unsigned short* g, unsigned short* l) {
    __builtin_amdgcn_global_load_lds(
        (const __attribute__((address_space(1))) unsigned int*)(uintptr_t)g,
        (__attribute__((address_space(3))) unsigned int*)(uintptr_t)l,
        16, 0, 0);
}

// ---------------------------------------------------------------------------
// Pre-kernel: convert sent (T,B,E) fp32 and W (3H,E) fp32 to bf16 in ws.
// ---------------------------------------------------------------------------
__global__ void convert_inputs(const float* __restrict__ X,
                               const float* __restrict__ W,
                               unsigned short* __restrict__ Xb,
                               unsigned short* __restrict__ Wb) {
    const int nX = TT * BB * EE;              // 8,388,608 (divisible by 8)
    int i = (blockIdx.x * blockDim.x + threadIdx.x) * 8;
    const float* src;
    unsigned short* dst;
    int j;
    if (i < nX) { src = X; dst = Xb; j = i; }
    else        { src = W; dst = Wb; j = i - nX; }
    float4 v0 = *(const float4*)(src + j);
    float4 v1 = *(const float4*)(src + j + 4);
    union { short8 s; unsigned u[4]; } o;
    o.u[0] = cvtpk_bf16(v0.x, v0.y);
    o.u[1] = cvtpk_bf16(v0.z, v0.w);
    o.u[2] = cvtpk_bf16(v1.x, v1.y);
    o.u[3] = cvtpk_bf16(v1.z, v1.w);
    *(short8*)(dst + j) = o.s;
}

// ---------------------------------------------------------------------------
// Fused QRNN kernel — R9: 4-way K-split, 8 waves/block, 4 waves/SIMD.
//
// R4 post-mortem: redundant tails REGRESSED (more exch traffic, no per-SIMD
// tail relief). R1/R3/R4 all pinned at 2 waves/SIMD by the 196-reg budget
// (100 VGPR + 96 AGPR W-pin). Total = 128 region-slots x region_time; the
// ~3200-cyc region is mostly latency exposure at 2 waves/SIMD.
//
// This round: K split 4 ways (s = wv>>1 in 0..3, 128 E each), 2 h-tiles
// (hi = wv&1). W pin 96 -> 48 AGPRs; per-wave peak ~115 regs <= 128 ->
// __launch_bounds__(512,4) gives 4 waves/SIMD (16 waves/CU, 2 blocks).
// Twice the resident waves = 2x latency hiding for the SAME total work.
//
// Tail (activations + scan + carry + max): 2 per block (one per hi), run by
// designated TAIL WAVES, assigned by block parity so co-resident blocks of
// opposite parity put tails on disjoint SIMDs:
//   parity 0: wv0 (s0,hi0) -> SIMD0, wv5 (s2,hi1) -> SIMD1
//   parity 1: wv2 (s1,hi0) -> SIMD2, wv7 (s3,hi1) -> SIMD3
// Tail wave keeps its OWN chunk partial in regs (rotation state own*);
// the other 3 k-quarters publish to a 3-slot ping-pong exch.
//
// Hazards:
//  (1) publish(ch) vs tail-read(ch) in region ch+1: lgkmcnt(0)+BAR(ch).
//  (2) tail-read(ch-1) in region ch vs re-publish of slot (ch-1)&1 in
//      region ch+1: reads retired at BAR(ch) before region ch+1 begins.
//  (3) X dbuf WAR: stage(ch+1) writes buf^1; its last readers ran region
//      ch-1 and retired (lgkmcnt 0) at BAR(ch-1) before any wave stages.
//  (4) X RAW: region ch+1 reads what stage(ch+1) wrote: vmcnt(0) at BAR(ch).
//  (5) Barriers wave-uniform (ch uniform; tail conditionals contain no
//      barrier). All 8 waves hit BAR once per region.
//  (6) carry/vmax/bias live only in tail waves; own* rotation harmless
//      elsewhere.
// ---------------------------------------------------------------------------
__launch_bounds__(512, 4)
__global__ void qrnn_fused(const unsigned short* __restrict__ Xb, // bf16 (T,B,E)
                           const unsigned short* __restrict__ Wb, // bf16 (3H,E)
                           const float* __restrict__ bias,        // (3H)
                           float* __restrict__ out)               // (B,H) fp32
{
    __shared__ unsigned short xlds[2 * XBUF];      // 33,792 B
    __shared__ float exch[2][2][3][64][12];        // 36,864 B  (total 70,656 B)

    const int tid  = threadIdx.x;
    const int wv   = tid >> 6;         // wave 0..7  (SIMD = wv & 3)
    const int lane = tid & 63;
    const int q    = lane >> 4;        // quad 0..3
    const int c    = lane & 15;        // column within 16x16 tile
    const int s    = wv >> 1;          // k-quarter 0..3 (128 E each)
    const int hi   = wv & 1;           // h-tile 0..1

    // XCD-aware swizzle: 2048 blocks = 8 XCDs x 4 batches x 64 h-groups.
    const int id   = blockIdx.x;       // 0..2047
    const int xcd  = id & 7;
    const int slot = id >> 3;          // 0..255 within this XCD
    const int b    = xcd * 4 + (slot >> 6);   // 4 batches per XCD
    const int hgrp = slot & 63;               // 64 h-groups per batch
    const int h    = hgrp * 32 + hi * 16 + c;

    // Tail-wave assignment by block parity (see header).
    const int  p      = slot & 1;
    const int  ts     = (hi == 0) ? p : 2 + p;   // the tailing s for this hi
    const bool isTail = (s == ts);

    // ---- preload W fragments (this wave's K quarter); pin into AGPRs ----
    // B-frag layout for 16x16x32: lane holds n = lane&15 (= h), k = q*8 + j.
    short8 wz[4], wf[4], wo[4];
    {
        const unsigned short* wzr = Wb + (size_t)h * EE            + s * 128;
        const unsigned short* wfr = Wb + (size_t)(HH + h) * EE     + s * 128;
        const unsigned short* wor = Wb + (size_t)(2 * HH + h) * EE + s * 128;
#pragma unroll
        for (int k = 0; k < 4; ++k) {
            int e0 = k * 32 + q * 8;
            wz[k] = *(const short8*)(wzr + e0);
            wf[k] = *(const short8*)(wfr + e0);
            wo[k] = *(const short8*)(wor + e0);
        }
    }
#pragma unroll
    for (int k = 0; k < 4; ++k) {
        asm volatile("" : "+a"(wz[k]), "+a"(wf[k]), "+a"(wo[k]));
    }

    // Bias (consumed only by tail waves, added once to the full sum).
    const float b0 = bias[h];
    const float b1 = bias[HH + h];
    const float b2 = bias[2 * HH + h];

    float carry = 0.0f;
    float vmax  = -1e30f;

    // ---- staging: wave wv owns rows wv*2, wv*2+1 of each 16-t chunk ----
    const unsigned short* g0 = Xb + ((size_t)(wv * 2) * BB + b) * EE + lane * 8;
    unsigned short* l0 = &xlds[(wv * 2) * XROW];

    auto stage = [&](int n, int slt) {
        const unsigned short* g = g0 + (size_t)n * (16 * BB * EE);
        unsigned short* l = l0 + slt * XBUF;
#pragma unroll
        for (int i = 0; i < 2; ++i)
            load_lds16(g + (size_t)i * (BB * EE), l + i * XROW);
    };

    // tail for one chunk's fully-summed (bias-included) accumulators.
    auto do_tail = [&](f32x4 az, f32x4 af, f32x4 ao) {
        float aa[4], mm[4], oo[4];
#pragma unroll
        for (int r = 0; r < 4; ++r) {
            float e2 = fast_exp(2.0f * az[r]);
            float z  = 1.0f - 2.0f * fast_rcp(e2 + 1.0f);  // tanh
            float f  = fast_rcp(1.0f + fast_exp(-af[r]));  // sigmoid
            float o  = fast_rcp(1.0f + fast_exp(-ao[r]));  // sigmoid
            aa[r] = f * z;
            mm[r] = 1.0f - f;
            oo[r] = o;
        }

        // affine scan: compose 4 steps, scan across quads
        float A = aa[0], M = mm[0];
#pragma unroll
        for (int r = 1; r < 4; ++r) { A = aa[r] + mm[r] * A; M = mm[r] * M; }

        float Ap = __shfl_up(A, 16, 64), Mp = __shfl_up(M, 16, 64);
        if (q >= 1) { A = A + M * Ap; M = M * Mp; }
        Ap = __shfl_up(A, 32, 64); Mp = __shfl_up(M, 32, 64);
        if (q >= 2) { A = A + M * Ap; M = M * Mp; }
        float Ae = __shfl_up(A, 16, 64), Me = __shfl_up(M, 16, 64);
        if (q == 0) { Ae = 0.0f; Me = 1.0f; }
        float cc = Ae + Me * carry;

#pragma unroll
        for (int r = 0; r < 4; ++r) {
            cc = aa[r] + mm[r] * cc;
            vmax = fmaxf(vmax, oo[r] * cc);
        }

        float cend = A + M * carry;
        carry = __shfl(cend, 48 + c, 64);
    };

    stage(0, 0);
    BAR_VM0();

    f32x4 ownz, ownf, owno;   // tail wave's own partial of chunk ch-1

    for (int ch = 0; ch < 32; ++ch) {
        const int buf = ch & 1;
        if (ch < 31) stage(ch + 1, buf ^ 1);

        // ---- this wave's 12 MFMAs (3 gates x 4 k-frags, depth-4 chains) --
        const unsigned short* Abase = &xlds[buf * XBUF + c * XROW + s * 128 + q * 8];
        f32x4 az = {0.f, 0.f, 0.f, 0.f};
        f32x4 af = {0.f, 0.f, 0.f, 0.f};
        f32x4 ao = {0.f, 0.f, 0.f, 0.f};
#pragma unroll
        for (int k = 0; k < 4; ++k) {
            short8 a = *(const short8*)(Abase + k * 32);
            az = __builtin_amdgcn_mfma_f32_16x16x32_bf16(a, wz[k], az, 0, 0, 0);
            af = __builtin_amdgcn_mfma_f32_16x16x32_bf16(a, wf[k], af, 0, 0, 0);
            ao = __builtin_amdgcn_mfma_f32_16x16x32_bf16(a, wo[k], ao, 0, 0, 0);
        }

        // ---- non-tail waves publish into this chunk's ping-pong slot ----
        if (!isTail) {
            const int sl = s - (s > ts ? 1 : 0);   // compact 3-slot index
            float* e = &exch[ch & 1][hi][sl][lane][0];
            *(f32x4*)(e)     = az;
            *(f32x4*)(e + 4) = af;
            *(f32x4*)(e + 8) = ao;
        }

        // ---- tail(ch-1) in tail waves: own(prev) + 3 exch slots + bias ---
        if (isTail && ch > 0) {
            const float* e0 = &exch[(ch - 1) & 1][hi][0][lane][0];
            const float* e1 = &exch[(ch - 1) & 1][hi][1][lane][0];
            const float* e2 = &exch[(ch - 1) & 1][hi][2][lane][0];
            f32x4 sz = ownz + *(const f32x4*)(e0);
            f32x4 sf = ownf + *(const f32x4*)(e0 + 4);
            f32x4 so = owno + *(const f32x4*)(e0 + 8);
            sz = sz + *(const f32x4*)(e1);  sz = sz + *(const f32x4*)(e2);
            sf = sf + *(const f32x4*)(e1 + 4);  sf = sf + *(const f32x4*)(e2 + 4);
            so = so + *(const f32x4*)(e1 + 8);  so = so + *(const f32x4*)(e2 + 8);
#pragma unroll
            for (int r = 0; r < 4; ++r) { sz[r] += b0; sf[r] += b1; so[r] += b2; }
            do_tail(sz, sf, so);
        }

        ownz = az; ownf = af; owno = ao;

        BAR_VM0();   // one barrier per region (see hazard list)
    }

    // ---- epilogue: tail(31) (published before the final barrier) ----
    if (isTail) {
        const float* e0 = &exch[31 & 1][hi][0][lane][0];
        const float* e1 = &exch[31 & 1][hi][1][lane][0];
        const float* e2 = &exch[31 & 1][hi][2][lane][0];
        f32x4 sz = ownz + *(const f32x4*)(e0);
        f32x4 sf = ownf + *(const f32x4*)(e0 + 4);
        f32x4 so = owno + *(const f32x4*)(e0 + 8);
        sz = sz + *(const f32x4*)(e1);  sz = sz + *(const f32x4*)(e2);
        sf = sf + *(const f32x4*)(e1 + 4);  sf = sf + *(const f32x4*)(e2 + 4);
        so = so + *(const f32x4*)(e1 + 8);  so = so + *(const f32x4*)(e2 + 8);
#pragma unroll
        for (int r = 0; r < 4; ++r) { sz[r] += b0; sf[r] += b1; so[r] += b2; }
        do_tail(sz, sf, so);

        vmax = fmaxf(vmax, __shfl_xor(vmax, 16, 64));
        vmax = fmaxf(vmax, __shfl_xor(vmax, 32, 64));
        if (q == 0) out[(size_t)b * HH + h] = vmax;
    }
}

// ---------------------------------------------------------------------------
extern "C" void kernel_launch(void* const* d_in, const int* in_sizes, int n_in,
                              void* d_out, int out_size, void* d_ws, size_t ws_size,
                              hipStream_t stream) {
    const float* sent = (const float*)d_in[0];
    // d_in[1] = lengths (unused by the math)
    const float* W    = (const float*)d_in[2];
    const float* bias = (const float*)d_in[3];
    float* out        = (float*)d_out;

    const int nX = TT * BB * EE;        // 8,388,608
    const int nW = 3 * HH * EE;         // 3,145,728
    unsigned short* Xb = (unsigned short*)d_ws;
    unsigned short* Wb = Xb + nX;       // 16 MiB offset, 16B-aligned

    int totalVec = (nX + nW) / 8;       // 1,441,792 threads, exact cover
    convert_inputs<<<totalVec / 256, 256, 0, stream>>>(sent, W, Xb, Wb);

    dim3 grid(2048);                    // 1-D: swizzled to (xcd, b, hgrp) in-kernel
    qrnn_fused<<<grid, 512, 0, stream>>>(Xb, Wb, bias, out);
}

// Round 6
// 238.319 us; speedup vs baseline: 1.1136x; 1.0898x over previous
//
#include <hip/hip_runtime.h>
#include <stdint.h>

#define TT 512
#define BB 32
#define EE 512
#define HH 2048

typedef __attribute__((ext_vector_type(8))) short short8;   // 8 x bf16 (4 VGPRs)
typedef __attribute__((ext_vector_type(4))) float f32x4;    // MFMA accumulator

// LDS geometry (in shorts)
#define XROW 528            // 512 data + 16 pad: measured 0 bank conflicts (R1/R3/R5);
                            // 520 gave 8.4M conflicts. Row stride 1056 B = 16*66.
#define XBUF (16 * XROW)    // one 16-t chunk buffer = 8448 shorts (16.5 KB)

// Barrier: drain DMA (vmcnt) + all DS ops (lgkm), then s_barrier.
// R3 measured counted-vmcnt vs vmcnt(0) NEUTRAL (DMA issued at region top
// lands before the region's tail completes) -> keep the simple form.
#define BAR_VM0() asm volatile("s_waitcnt vmcnt(0) lgkmcnt(0)\n\ts_barrier" ::: "memory")

static __device__ __forceinline__ float fast_exp(float x) {
    return __builtin_amdgcn_exp2f(x * 1.44269504f);
}
static __device__ __forceinline__ float fast_rcp(float x) {
    return __builtin_amdgcn_rcpf(x);
}

// Packed fp32->bf16 RNE convert: 1 instr per 2 elements.
static __device__ __forceinline__ unsigned cvtpk_bf16(float lo, float hi) {
    unsigned r;
    asm("v_cvt_pk_bf16_f32 %0, %1, %2" : "=v"(r) : "v"(lo), "v"(hi));
    return r;
}

// Async global->LDS DMA, 16 B/lane (wave-uniform LDS base + lane*16).
static __device__ __forceinline__ void load_lds16(const unsigned short* g, unsigned short* l) {
    __builtin_amdgcn_global_load_lds(
        (const __attribute__((address_space(1))) unsigned int*)(uintptr_t)g,
        (__attribute__((address_space(3))) unsigned int*)(uintptr_t)l,
        16, 0, 0);
}

// ---------------------------------------------------------------------------
// Pre-kernel: convert sent (T,B,E) fp32 and W (3H,E) fp32 to bf16 in ws.
// Grid-stride (2048 blocks) to cut dispatch overhead vs the 5633-block
// one-shot version.
// ---------------------------------------------------------------------------
__global__ void convert_inputs(const float* __restrict__ X,
                               const float* __restrict__ W,
                               unsigned short* __restrict__ Xb,
                               unsigned short* __restrict__ Wb) {
    const int nX = TT * BB * EE;              // 8,388,608 (divisible by 8)
    const int nT = (nX + 3 * HH * EE) / 8;    // total short8 groups: 1,441,792
    const int stride = gridDim.x * blockDim.x;
    for (int g = blockIdx.x * blockDim.x + threadIdx.x; g < nT; g += stride) {
        int i = g * 8;
        const float* src;
        unsigned short* dst;
        int j;
        if (i < nX) { src = X; dst = Xb; j = i; }
        else        { src = W; dst = Wb; j = i - nX; }
        float4 v0 = *(const float4*)(src + j);
        float4 v1 = *(const float4*)(src + j + 4);
        union { short8 s; unsigned u[4]; } o;
        o.u[0] = cvtpk_bf16(v0.x, v0.y);
        o.u[1] = cvtpk_bf16(v0.z, v0.w);
        o.u[2] = cvtpk_bf16(v1.x, v1.y);
        o.u[3] = cvtpk_bf16(v1.z, v1.w);
        *(short8*)(dst + j) = o.s;
    }
}

// ---------------------------------------------------------------------------
// Fused QRNN kernel — R10: R1 geometry + tail PIPELINE-SPLIT across waves.
//
// Evidence so far: R3 (counted vmcnt) neutral -> DMA drain not exposed.
// R4 (redundant tails) regressed. R5 (4-way split, occupancy 20->41%)
// neutral-worse -> TLP not the constraint. Conclusion: the region critical
// path is the TAIL WAVE's serial program (~800 cyc: 24 trans + serial
// shuffle scan + prefix), which every barrier waits on, 32x per block.
//
// This round splits the tail into two stages on DIFFERENT waves, pipelined
// across regions (3-stage chunk pipeline raw -> act -> scan):
//   region ch  : all waves MFMA(ch); s=0 publishes raw partials(ch).
//   region ch+1: s=1 sums raw(ch)+own(ch)+bias, computes ACTIVATIONS
//                (12 exp + 12 rcp, ~half the tail), publishes aa/mm/oo(ch).
//   region ch+2: s=0 runs the SCAN half (compose, cross-quad shuffles,
//                prefix, vmax, carry) on act(ch).
// Each wave now carries ~MFMA + half-tail per region instead of one wave
// carrying the whole tail while the partner idles at the barrier.
//
// carry/vmax stay private to s=0 (scan stage). Bias enters at the act
// stage (s=1). Exchange: raw[2] (s=0 -> s=1) and act[2] (s=1 -> s=0)
// ping-pong buffers, lane-aligned (no shuffles in the exchange).
//
// Hazards:
//  (1) raw(ch) published region ch (s=0), read region ch+1 (s=1):
//      lgkmcnt(0)+BAR(ch). Slot (ch&1) rewritten region ch+2; reads
//      retired at BAR(ch+1).
//  (2) act(ch) published region ch+1 (s=1) to slot ch&1, read region ch+2
//      (s=0): BAR(ch+1) orders. Slot rewritten region ch+3 (act(ch+2));
//      reads retired at BAR(ch+2).
//  (3) X dbuf WAR/RAW: unchanged from R1 (stage ch+1 in region ch,
//      consumed region ch+1; vmcnt(0)+lgkmcnt(0) at each barrier).
//  (4) Barriers wave-uniform: ch uniform; conditionals contain no barrier.
//  (5) s=1 keeps its own raw partial of the previous chunk in regs
//      (rotation prev*); s=0 keeps carry/vmax.
// ---------------------------------------------------------------------------
__launch_bounds__(256, 2)
__global__ void qrnn_fused(const unsigned short* __restrict__ Xb, // bf16 (T,B,E)
                           const unsigned short* __restrict__ Wb, // bf16 (3H,E)
                           const float* __restrict__ bias,        // (3H)
                           float* __restrict__ out)               // (B,H) fp32
{
    __shared__ unsigned short xlds[2 * XBUF];      // 33,792 B
    __shared__ float rawx[2][2][64][12];           // 12,288 B (s=0 -> s=1)
    __shared__ float actx[2][2][64][12];           // 12,288 B (s=1 -> s=0)
                                                   // total 58,368 B

    const int tid  = threadIdx.x;
    const int wv   = tid >> 6;         // wave 0..3
    const int lane = tid & 63;
    const int q    = lane >> 4;        // quad 0..3
    const int c    = lane & 15;        // column within 16x16 tile
    const int hi   = wv >> 1;          // h-tile 0..1
    const int s    = wv & 1;           // k-half 0..1

    // XCD-aware swizzle: 2048 blocks = 8 XCDs x 4 batches x 64 h-groups.
    const int id   = blockIdx.x;       // 0..2047
    const int xcd  = id & 7;
    const int slot = id >> 3;          // 0..255 within this XCD
    const int b    = xcd * 4 + (slot >> 6);   // 4 batches per XCD
    const int hgrp = slot & 63;               // 64 h-groups per batch
    const int h    = hgrp * 32 + hi * 16 + c;

    // ---- preload W fragments (this wave's K half); pin into AGPRs ----
    // B-frag layout for 16x16x32: lane holds n = lane&15 (= h), k = q*8 + j.
    short8 wz[8], wf[8], wo[8];
    {
        const unsigned short* wzr = Wb + (size_t)h * EE            + s * 256;
        const unsigned short* wfr = Wb + (size_t)(HH + h) * EE     + s * 256;
        const unsigned short* wor = Wb + (size_t)(2 * HH + h) * EE + s * 256;
#pragma unroll
        for (int k = 0; k < 8; ++k) {
            int e0 = k * 32 + q * 8;
            wz[k] = *(const short8*)(wzr + e0);
            wf[k] = *(const short8*)(wfr + e0);
            wo[k] = *(const short8*)(wor + e0);
        }
    }
#pragma unroll
    for (int k = 0; k < 8; ++k) {
        asm volatile("" : "+a"(wz[k]), "+a"(wf[k]), "+a"(wo[k]));
    }

    // Bias consumed at the act stage (s=1).
    const float b0 = bias[h];
    const float b1 = bias[HH + h];
    const float b2 = bias[2 * HH + h];

    float carry = 0.0f;    // live in s=0 (scan stage)
    float vmax  = -1e30f;  // live in s=0

    // ---- staging: wave wv owns rows wv*4 .. wv*4+3 of each 16-t chunk ----
    const unsigned short* g0 = Xb + ((size_t)(wv * 4) * BB + b) * EE + lane * 8;
    unsigned short* l0 = &xlds[(wv * 4) * XROW];

    auto stage = [&](int n, int slt) {
        const unsigned short* g = g0 + (size_t)n * (16 * BB * EE);
        unsigned short* l = l0 + slt * XBUF;
#pragma unroll
        for (int i = 0; i < 4; ++i)
            load_lds16(g + (size_t)i * (BB * EE), l + i * XROW);
    };

    // ---- act stage (s=1): summed partials + bias -> aa/mm/oo, publish ----
    auto do_act = [&](int n, f32x4 sz, f32x4 sf, f32x4 so) {
        float* e = &actx[n & 1][hi][lane][0];
#pragma unroll
        for (int r = 0; r < 4; ++r) {
            float zz = sz[r] + b0;
            float ff = sf[r] + b1;
            float oo = so[r] + b2;
            float e2 = fast_exp(2.0f * zz);
            float z  = 1.0f - 2.0f * fast_rcp(e2 + 1.0f);  // tanh
            float f  = fast_rcp(1.0f + fast_exp(-ff));     // sigmoid
            float o  = fast_rcp(1.0f + fast_exp(-oo));     // sigmoid
            e[r]     = f * z;        // aa
            e[4 + r] = 1.0f - f;     // mm
            e[8 + r] = o;            // oo
        }
    };

    // ---- scan stage (s=0): compose + cross-quad scan + prefix/vmax ----
    auto do_scan = [&](int n) {
        const float* e = &actx[n & 1][hi][lane][0];
        float aa[4], mm[4], oo[4];
#pragma unroll
        for (int r = 0; r < 4; ++r) {
            aa[r] = e[r];
            mm[r] = e[4 + r];
            oo[r] = e[8 + r];
        }

        float A = aa[0], M = mm[0];
#pragma unroll
        for (int r = 1; r < 4; ++r) { A = aa[r] + mm[r] * A; M = mm[r] * M; }

        float Ap = __shfl_up(A, 16, 64), Mp = __shfl_up(M, 16, 64);
        if (q >= 1) { A = A + M * Ap; M = M * Mp; }
        Ap = __shfl_up(A, 32, 64); Mp = __shfl_up(M, 32, 64);
        if (q >= 2) { A = A + M * Ap; M = M * Mp; }
        float Ae = __shfl_up(A, 16, 64), Me = __shfl_up(M, 16, 64);
        if (q == 0) { Ae = 0.0f; Me = 1.0f; }
        float cc = Ae + Me * carry;

#pragma unroll
        for (int r = 0; r < 4; ++r) {
            cc = aa[r] + mm[r] * cc;
            vmax = fmaxf(vmax, oo[r] * cc);
        }

        float cend = A + M * carry;
        carry = __shfl(cend, 48 + c, 64);
    };

    stage(0, 0);
    BAR_VM0();

    f32x4 prevz, prevf, prevo;   // s=1: own raw partial of chunk ch-1

    for (int ch = 0; ch < 32; ++ch) {
        const int buf = ch & 1;
        if (ch < 31) stage(ch + 1, buf ^ 1);

        // ---- a-frags for chunk ch (8 back-to-back b128) ----
        const unsigned short* Abase = &xlds[buf * XBUF + c * XROW + s * 256 + q * 8];
        short8 a[8];
#pragma unroll
        for (int k = 0; k < 8; ++k)
            a[k] = *(const short8*)(Abase + k * 32);

        // ---- MFMA burst: 24 MFMAs, 3 independent accumulator chains ----
        f32x4 az = {0.f, 0.f, 0.f, 0.f};
        f32x4 af = {0.f, 0.f, 0.f, 0.f};
        f32x4 ao = {0.f, 0.f, 0.f, 0.f};
#pragma unroll
        for (int k = 0; k < 8; ++k) {
            az = __builtin_amdgcn_mfma_f32_16x16x32_bf16(a[k], wz[k], az, 0, 0, 0);
            af = __builtin_amdgcn_mfma_f32_16x16x32_bf16(a[k], wf[k], af, 0, 0, 0);
            ao = __builtin_amdgcn_mfma_f32_16x16x32_bf16(a[k], wo[k], ao, 0, 0, 0);
        }

        if (s == 0) {
            // publish raw(ch) for the act stage next region
            float* e = &rawx[ch & 1][hi][lane][0];
            *(f32x4*)(e)     = az;
            *(f32x4*)(e + 4) = af;
            *(f32x4*)(e + 8) = ao;

            // scan(ch-2) from act published last region
            if (ch > 1) do_scan(ch - 2);
        } else {
            // act(ch-1): own rotation + partner raw + bias -> activations
            if (ch > 0) {
                const float* e = &rawx[(ch - 1) & 1][hi][lane][0];
                f32x4 sz = prevz + *(const f32x4*)(e);
                f32x4 sf = prevf + *(const f32x4*)(e + 4);
                f32x4 so = prevo + *(const f32x4*)(e + 8);
                do_act(ch - 1, sz, sf, so);
            }
            prevz = az; prevf = af; prevo = ao;
        }

        BAR_VM0();   // one barrier per region (hazards (1)-(4))
    }

    // ---- epilogue: act(31), then scan(30), scan(31) ----
    if (s == 1) {
        const float* e = &rawx[31 & 1][hi][lane][0];
        f32x4 sz = prevz + *(const f32x4*)(e);
        f32x4 sf = prevf + *(const f32x4*)(e + 4);
        f32x4 so = prevo + *(const f32x4*)(e + 8);
        do_act(31, sz, sf, so);
    }
    BAR_VM0();

    if (s == 0) {
        do_scan(30);   // act(30) published in region 31
        do_scan(31);   // act(31) published in epilogue

        vmax = fmaxf(vmax, __shfl_xor(vmax, 16, 64));
        vmax = fmaxf(vmax, __shfl_xor(vmax, 32, 64));
        if (q == 0) out[(size_t)b * HH + h] = vmax;
    }
}

// ---------------------------------------------------------------------------
extern "C" void kernel_launch(void* const* d_in, const int* in_sizes, int n_in,
                              void* d_out, int out_size, void* d_ws, size_t ws_size,
                              hipStream_t stream) {
    const float* sent = (const float*)d_in[0];
    // d_in[1] = lengths (unused by the math)
    const float* W    = (const float*)d_in[2];
    const float* bias = (const float*)d_in[3];
    float* out        = (float*)d_out;

    const int nX = TT * BB * EE;        // 8,388,608
    const int nW = 3 * HH * EE;         // 3,145,728
    unsigned short* Xb = (unsigned short*)d_ws;
    unsigned short* Wb = Xb + nX;       // 16 MiB offset, 16B-aligned

    convert_inputs<<<2048, 256, 0, stream>>>(sent, W, Xb, Wb);

    dim3 grid(2048);                    // 1-D: swizzled to (xcd, b, hgrp) in-kernel
    qrnn_fused<<<grid, 256, 0, stream>>>(Xb, Wb, bias, out);
}